// Round 5
// baseline (409.092 us; speedup 1.0000x reference)
//
#include <hip/hip_runtime.h>

typedef __attribute__((ext_vector_type(4))) float f32x4;
typedef __attribute__((ext_vector_type(8))) __bf16 bf16x8;
typedef __attribute__((ext_vector_type(8))) unsigned short ushort8;

static __device__ __forceinline__ unsigned short f2bf(float f) {
    unsigned int u = __float_as_uint(f);
    u += 0x7fffu + ((u >> 16) & 1u);   // round-to-nearest-even
    return (unsigned short)(u >> 16);
}
static __device__ __forceinline__ float bf2f(unsigned short u) {
    return __uint_as_float((unsigned int)u << 16);
}
static __device__ __forceinline__ bf16x8 as_bf(ushort8 v) {
    union { ushort8 u; bf16x8 b; } x; x.u = v; return x.b;
}
// async global->LDS, 16B per lane. LDS dest = wave-uniform base + lane*16.
static __device__ __forceinline__ void gll16(const void* g, void* l) {
    __builtin_amdgcn_global_load_lds(
        (const __attribute__((address_space(1))) void*)g,
        (__attribute__((address_space(3))) void*)l, 16, 0, 0);
}

// ---------------------------------------------------------------------------
// f32 -> bf16 convert (8 elems/thread)
// ---------------------------------------------------------------------------
__global__ void cvt_bf16(const float* __restrict__ in, unsigned short* __restrict__ out,
                         int n8) {
    int i = blockIdx.x * 256 + threadIdx.x;
    if (i >= n8) return;
    const float4* p = (const float4*)(in + (size_t)i * 8);
    float4 a = p[0], b = p[1];
    ushort8 o = { f2bf(a.x), f2bf(a.y), f2bf(a.z), f2bf(a.w),
                  f2bf(b.x), f2bf(b.y), f2bf(b.z), f2bf(b.w) };
    *(ushort8*)(out + (size_t)i * 8) = o;
}

// ---------------------------------------------------------------------------
// transpose + convert: in [K][N] f32 -> out [N][K] bf16. 64x64 tiles.
// ---------------------------------------------------------------------------
__global__ void tconv_bf16(const float* __restrict__ in, unsigned short* __restrict__ out,
                           int K, int N) {
    __shared__ float t[64][65];
    const int tid = threadIdx.x;
    const int n0 = blockIdx.x * 64, k0 = blockIdx.y * 64;
#pragma unroll
    for (int i = 0; i < 4; i++) {
        int idx = tid + 256 * i;
        int r = idx >> 4, c4 = (idx & 15) * 4;
        float4 v = *(const float4*)(in + (size_t)(k0 + r) * N + n0 + c4);
        t[r][c4] = v.x; t[r][c4 + 1] = v.y; t[r][c4 + 2] = v.z; t[r][c4 + 3] = v.w;
    }
    __syncthreads();
#pragma unroll
    for (int i = 0; i < 2; i++) {
        int idx = tid + 256 * i;
        int nl = idx >> 3, k8 = (idx & 7) * 8;
        ushort8 o;
#pragma unroll
        for (int j = 0; j < 8; j++) o[j] = f2bf(t[k8 + j][nl]);
        *(ushort8*)(out + (size_t)(n0 + nl) * K + k0 + k8) = o;
    }
}

// ---------------------------------------------------------------------------
// GEMM (m97-structure): C[M,N] = A[M,K](bf16) * BT[N,K](bf16)^T + bias
// EPI=0: scatter to per-head bf16 Q/K/V via LDS roundtrip; Q pre-scaled by
//        0.125*log2(e) so attention can use bare v_exp_f32 (exp2).
// EPI=1: plain f32 C
// ---------------------------------------------------------------------------
template <int EPI>
__global__ __launch_bounds__(256, 2)
void gemm_bf16(const unsigned short* __restrict__ A,
               const unsigned short* __restrict__ BT,
               const float* __restrict__ bias,
               unsigned short* __restrict__ qh, unsigned short* __restrict__ kh,
               unsigned short* __restrict__ vh,
               float* __restrict__ Cf,
               int K, int mtiles, int Ncols)
{
    __shared__ unsigned short smem[2 * 128 * 64];
    unsigned short* As = smem;
    unsigned short* Bs = smem + 128 * 64;

    const int tid = threadIdx.x;
    const int wid = tid >> 6, lane = tid & 63;
    const int g = lane >> 4, c = lane & 15;
    const int wr = (wid >> 1) * 64, wc = (wid & 1) * 64;

    const int nwg = gridDim.x;
    const int swz = ((int)blockIdx.x & 7) * (nwg >> 3) + ((int)blockIdx.x >> 3);
    const int bm = (swz % mtiles) * 128;
    const int bn = (swz / mtiles) * 128;

    const int srow = lane >> 3;
    const int scol8 = ((lane & 7) ^ srow) * 8;
    const size_t arow0 = (size_t)(bm + wid * 8 + srow);
    const size_t brow0 = (size_t)(bn + wid * 8 + srow);

    f32x4 acc[4][4] = {};

    for (int k0 = 0; k0 < K; k0 += 64) {
        __syncthreads();
#pragma unroll
        for (int t = 0; t < 4; t++) {
            gll16(A + (arow0 + t * 32) * K + k0 + scol8,
                  (char*)As + t * 4096 + wid * 1024);
            gll16(BT + (brow0 + t * 32) * K + k0 + scol8,
                  (char*)Bs + t * 4096 + wid * 1024);
        }
        __syncthreads();
#pragma unroll
        for (int ks = 0; ks < 2; ks++) {
            bf16x8 af[4], bfr[4];
#pragma unroll
            for (int mi = 0; mi < 4; mi++) {
                int row = wr + mi * 16 + c;
                int off = row * 128 + ((ks * 64 + g * 16) ^ ((c & 7) << 4));
                af[mi] = as_bf(*(const ushort8*)((const char*)As + off));
            }
#pragma unroll
            for (int ni = 0; ni < 4; ni++) {
                int row = wc + ni * 16 + c;
                int off = row * 128 + ((ks * 64 + g * 16) ^ ((c & 7) << 4));
                bfr[ni] = as_bf(*(const ushort8*)((const char*)Bs + off));
            }
#pragma unroll
            for (int mi = 0; mi < 4; mi++)
#pragma unroll
                for (int ni = 0; ni < 4; ni++)
                    acc[mi][ni] = __builtin_amdgcn_mfma_f32_16x16x32_bf16(
                        af[mi], bfr[ni], acc[mi][ni], 0, 0, 0);
        }
    }

    if (EPI == 1) {
#pragma unroll
        for (int mi = 0; mi < 4; mi++)
#pragma unroll
            for (int ni = 0; ni < 4; ni++)
#pragma unroll
                for (int r = 0; r < 4; r++) {
                    int m = bm + wr + mi * 16 + g * 4 + r;
                    int n = bn + wc + ni * 16 + c;
                    Cf[(size_t)m * Ncols + n] = acc[mi][ni][r] + bias[n];
                }
    } else {
#pragma unroll
        for (int nh = 0; nh < 2; nh++) {
            int n0 = bn + nh * 64;
            int region = n0 >> 10;
            float qscale = (region == 0) ? 0.1803368801f : 1.0f;  // 0.125*log2(e)
            __syncthreads();
            if ((wid & 1) == nh) {
#pragma unroll
                for (int mi = 0; mi < 4; mi++)
#pragma unroll
                    for (int ni = 0; ni < 4; ni++)
#pragma unroll
                        for (int r = 0; r < 4; r++) {
                            int row = wr + mi * 16 + g * 4 + r;
                            int col = ni * 16 + c;
                            float v = (acc[mi][ni][r] + bias[n0 + col]) * qscale;
                            smem[row * 64 + col] = f2bf(v);
                        }
            }
            __syncthreads();
            int h = (n0 & 1023) >> 6;
            unsigned short* dst = region == 0 ? qh : region == 1 ? kh : vh;
#pragma unroll
            for (int i = 0; i < 4; i++) {
                int idx = tid + 256 * i;
                int row = idx >> 3, c8 = (idx & 7) * 8;
                ushort8 v = *(const ushort8*)&smem[row * 64 + c8];
                int m = bm + row;
                int b = m >> 10, l = m & 1023;
                *(ushort8*)(dst + ((size_t)((b * 16 + h) * 1024 + l)) * 64 + c8) = v;
            }
        }
    }
}

// ---------------------------------------------------------------------------
// Single-pass attention, 16-row q-tiles. Block = (qt, bh), 4 waves.
// Swapped QK^T (mfma(K,Q)): lane holds 4 consecutive kcols of one q-row ->
// lane-local mask/sum, cvt_pk bf16 packing, one 8B P write. P unnormalized in
// LDS [16][1024] bf16; each wave does PV for its own 16-wide d-block (full K).
// LDS 48KB -> 3 blocks/CU.
// ---------------------------------------------------------------------------
__global__ __launch_bounds__(256, 3)
void attn_kernel(const unsigned short* __restrict__ qh,
                 const unsigned short* __restrict__ kh,
                 const unsigned short* __restrict__ vh,
                 float* __restrict__ attn, unsigned short* __restrict__ ob)
{
    __shared__ char smem[49152];
    char* P  = smem;                 // [16][1024] bf16, 16B-XOR swizzled
    char* Ks = smem + 32768;         // [64][64] bf16 swizzled
    char* Vt = smem + 40960;         // [64d][64k] bf16 swizzled

    const int qt = blockIdx.x;       // 0..63
    const int bh = blockIdx.y;       // b*16+h
    const int q0 = qt * 16;
    const int ntiles = (qt >> 2) + 1;

    const int tid = threadIdx.x, wid = tid >> 6, lane = tid & 63;
    const int g = lane >> 4, c = lane & 15;

    const size_t baseKV = (size_t)bh * (1024 * 64);

    // Q B-frag (pre-scaled in GEMM1): col c = qrow, k = ks*32 + g*8 + j
    const int qrow = q0 + c;
    bf16x8 qa[2];
    qa[0] = as_bf(*(const ushort8*)(qh + baseKV + (size_t)qrow * 64 + g * 8));
    qa[1] = as_bf(*(const ushort8*)(qh + baseKV + (size_t)qrow * 64 + 32 + g * 8));

    const int srow = lane >> 3;
    const int scol8 = ((lane & 7) ^ srow) * 8;   // pre-swizzled K source

    float lsum = 0.f;
    f32x4 oacc = {};

    for (int kt = 0; kt < ntiles; ++kt) {
        const unsigned short* kb = kh + baseKV + (size_t)kt * 4096;
        const unsigned short* vb = vh + baseKV + (size_t)kt * 4096;
        __syncthreads();   // prev tile's Ks/Vt/P consumers done
        gll16(kb + (size_t)(wid * 8 + srow) * 64 + scol8, Ks + wid * 1024);
        gll16(kb + (size_t)(32 + wid * 8 + srow) * 64 + scol8, Ks + 4096 + wid * 1024);
#pragma unroll
        for (int i = 0; i < 2; i++) {
            int cidx = tid + 256 * i;
            int row = cidx >> 3, col16 = cidx & 7;   // row = key, d0 = col16*8
            ushort8 v = *(const ushort8*)(vb + (size_t)row * 64 + col16 * 8);
#pragma unroll
            for (int j = 0; j < 8; j++) {
                int d = col16 * 8 + j;
                int off = d * 128 + ((row * 2) ^ ((d & 7) << 4));
                *(unsigned short*)(Vt + off) = v[j];
            }
        }
        __syncthreads();

        // swapped QK^T: A = K rows (kcols wid*16+c), B = Q  -> C[kcol][qrow]
        f32x4 s = {0.f, 0.f, 0.f, 0.f};
        {
            int krow = wid * 16 + c;
#pragma unroll
            for (int ks = 0; ks < 2; ks++) {
                int off = krow * 128 + ((ks * 64 + g * 16) ^ ((krow & 7) << 4));
                bf16x8 kf = as_bf(*(const ushort8*)(Ks + off));
                s = __builtin_amdgcn_mfma_f32_16x16x32_bf16(kf, qa[ks], s, 0, 0, 0);
            }
        }
        // lane: kcols kbase..kbase+3, q-row = qrow (= q0+c). exp2, mask, sum.
        int kbase = kt * 64 + wid * 16 + g * 4;
        float p0 = (kbase + 0 > qrow) ? 0.f : __builtin_amdgcn_exp2f(s[0]);
        float p1 = (kbase + 1 > qrow) ? 0.f : __builtin_amdgcn_exp2f(s[1]);
        float p2 = (kbase + 2 > qrow) ? 0.f : __builtin_amdgcn_exp2f(s[2]);
        float p3 = (kbase + 3 > qrow) ? 0.f : __builtin_amdgcn_exp2f(s[3]);
        lsum += (p0 + p1) + (p2 + p3);
        uint2 pw;
        asm("v_cvt_pk_bf16_f32 %0, %1, %2" : "=v"(pw.x) : "v"(p0), "v"(p1));
        asm("v_cvt_pk_bf16_f32 %0, %1, %2" : "=v"(pw.y) : "v"(p2), "v"(p3));
        *(uint2*)(P + c * 2048 + ((kbase * 2) ^ ((c & 7) << 4))) = pw;
        __syncthreads();   // P tile complete

        // PV: A = P[16 q-rows][64 k], B = Vt d-block wid -> O[qrow][d]
#pragma unroll
        for (int ks = 0; ks < 2; ks++) {
            int aoff = c * 2048 + (((kt * 64 + ks * 32 + g * 8) * 2) ^ ((c & 7) << 4));
            bf16x8 pa = as_bf(*(const ushort8*)(P + aoff));
            int d = wid * 16 + c;
            int voff = d * 128 + (((ks * 32 + g * 8) * 2) ^ ((d & 7) << 4));
            bf16x8 vf = as_bf(*(const ushort8*)(Vt + voff));
            oacc = __builtin_amdgcn_mfma_f32_16x16x32_bf16(pa, vf, oacc, 0, 0, 0);
        }
    }

    // row-sum reduce across g (lanes with same c), then across waves via LDS
    lsum += __shfl_xor(lsum, 16);
    lsum += __shfl_xor(lsum, 32);

    float* lS    = (float*)Ks;            // [4][16]
    float* rinvS = (float*)(Ks + 256);    // [16]
    char*  Obf   = Ks + 512;              // [16][64] bf16, swizzled
    __syncthreads();   // Ks/Vt dead
    if (lane < 16) lS[wid * 16 + lane] = lsum;
    __syncthreads();
    if (tid < 16)
        rinvS[tid] = 1.f / (lS[tid] + lS[16 + tid] + lS[32 + tid] + lS[48 + tid]);
    __syncthreads();

    // O normalize -> Obf (C layout: row = g*4+r, col d = wid*16+c)
#pragma unroll
    for (int r = 0; r < 4; r++) {
        int row = g * 4 + r;
        float o = oacc[r] * rinvS[row];
        int d = wid * 16 + c;
        int off = row * 128 + ((d * 2) ^ ((row & 7) << 4));
        *(unsigned short*)(Obf + off) = f2bf(o);
    }
    __syncthreads();
    if (tid < 128) {
        int row = tid >> 3, c8 = tid & 7;
        int off = row * 128 + ((c8 * 16) ^ ((row & 7) << 4));
        ushort8 v = *(const ushort8*)(Obf + off);
        const int b = bh >> 4, h = bh & 15;
        *(ushort8*)(ob + ((size_t)(b * 1024 + q0 + row)) * 1024 + h * 64 + c8 * 8) = v;
    }

    // attn store: 16 rows x 1024 cols f32, coalesced float4 (zeros past maxcol)
    {
        float* attnB = attn + (size_t)bh * (1024 * 1024) + (size_t)q0 * 1024;
        const int maxcol = ntiles * 64;
        const bool live = (tid * 4) < maxcol;
#pragma unroll 4
        for (int row = 0; row < 16; ++row) {
            float4 o = {0.f, 0.f, 0.f, 0.f};
            if (live) {
                float rinv = rinvS[row];
                int off = row * 2048 + ((tid * 8) ^ ((row & 7) << 4));
                ushort4 u = *(const ushort4*)(P + off);
                o.x = bf2f(u.x) * rinv; o.y = bf2f(u.y) * rinv;
                o.z = bf2f(u.z) * rinv; o.w = bf2f(u.w) * rinv;
            }
            *(float4*)(attnB + (size_t)row * 1024 + tid * 4) = o;
        }
    }
}

// ---------------------------------------------------------------------------
// LayerNorm(y + x) -> out
// ---------------------------------------------------------------------------
__global__ __launch_bounds__(256, 2)
void ln_kernel(const float* __restrict__ y, const float* __restrict__ x,
               const float* __restrict__ gamma, const float* __restrict__ beta,
               float* __restrict__ out)
{
    const int m = blockIdx.x;
    const int tid = threadIdx.x;
    const int wid = tid >> 6, lane = tid & 63;
    float4 vy = *(const float4*)(y + (size_t)m * 1024 + tid * 4);
    float4 vx = *(const float4*)(x + (size_t)m * 1024 + tid * 4);
    float4 v = {vy.x + vx.x, vy.y + vx.y, vy.z + vx.z, vy.w + vx.w};
    float s1 = v.x + v.y + v.z + v.w;
    float s2 = v.x * v.x + v.y * v.y + v.z * v.z + v.w * v.w;
#pragma unroll
    for (int d = 1; d < 64; d <<= 1) {
        s1 += __shfl_xor(s1, d);
        s2 += __shfl_xor(s2, d);
    }
    __shared__ float red1[4], red2[4];
    if (lane == 0) { red1[wid] = s1; red2[wid] = s2; }
    __syncthreads();
    float t1 = red1[0] + red1[1] + red1[2] + red1[3];
    float t2 = red2[0] + red2[1] + red2[2] + red2[3];
    float mean = t1 * (1.f / 1024.f);
    float var = t2 * (1.f / 1024.f) - mean * mean;
    float rstd = rsqrtf(var + 1e-5f);
    float4 g4 = *(const float4*)(gamma + tid * 4);
    float4 b4 = *(const float4*)(beta + tid * 4);
    float4 o;
    o.x = g4.x * (v.x - mean) * rstd + b4.x;
    o.y = g4.y * (v.y - mean) * rstd + b4.y;
    o.z = g4.z * (v.z - mean) * rstd + b4.z;
    o.w = g4.w * (v.w - mean) * rstd + b4.w;
    *(float4*)(out + (size_t)m * 1024 + tid * 4) = o;
}

// ---------------------------------------------------------------------------
extern "C" void kernel_launch(void* const* d_in, const int* in_sizes, int n_in,
                              void* d_out, int out_size, void* d_ws, size_t ws_size,
                              hipStream_t stream)
{
    const float* x      = (const float*)d_in[0];
    // d_in[1] = mask — causal, implemented analytically
    const float* W_qkv  = (const float*)d_in[2];
    const float* b_qkv  = (const float*)d_in[3];
    const float* W_proj = (const float*)d_in[4];
    const float* b_proj = (const float*)d_in[5];
    const float* gamma  = (const float*)d_in[6];
    const float* beta   = (const float*)d_in[7];

    float* out  = (float*)d_out;
    float* attn = out + (size_t)8 * 1024 * 1024;

    const size_t E = (size_t)8192 * 1024;
    unsigned short* ws = (unsigned short*)d_ws;
    unsigned short* qh     = ws;                     // bf16 [B][H][L][64]
    unsigned short* kh     = qh + E;
    unsigned short* vh     = kh + E;
    unsigned short* xb     = vh + E;                 // bf16 [8192][1024]
    unsigned short* wqkvT  = xb + E;                 // bf16 [3072][1024]
    unsigned short* wprojT = wqkvT + (size_t)3072 * 1024;
    unsigned short* ob     = wprojT + (size_t)1024 * 1024;  // bf16 [8192][1024]
    float* yb = (float*)(void*)qh;                   // overlays qh+kh (dead after attn)

    cvt_bf16<<<4096, 256, 0, stream>>>(x, xb, (int)(E / 8));
    tconv_bf16<<<dim3(48, 16), 256, 0, stream>>>(W_qkv, wqkvT, 1024, 3072);
    tconv_bf16<<<dim3(16, 16), 256, 0, stream>>>(W_proj, wprojT, 1024, 1024);

    gemm_bf16<0><<<1536, 256, 0, stream>>>(xb, wqkvT, b_qkv,
                                           qh, kh, vh, nullptr, 1024, 64, 3072);
    attn_kernel<<<dim3(64, 128), 256, 0, stream>>>(qh, kh, vh, attn, ob);
    gemm_bf16<1><<<512, 256, 0, stream>>>(ob, wprojT, b_proj,
                                          nullptr, nullptr, nullptr, yb, 1024, 64, 1024);
    ln_kernel<<<8192, 256, 0, stream>>>(yb, x, gamma, beta, out);
}

// Round 7
// 404.491 us; speedup vs baseline: 1.0114x; 1.0114x over previous
//
#include <hip/hip_runtime.h>

typedef __attribute__((ext_vector_type(4))) float f32x4;
typedef __attribute__((ext_vector_type(8))) __bf16 bf16x8;
typedef __attribute__((ext_vector_type(8))) unsigned short ushort8;

static __device__ __forceinline__ unsigned short f2bf(float f) {
    unsigned int u = __float_as_uint(f);
    u += 0x7fffu + ((u >> 16) & 1u);   // round-to-nearest-even
    return (unsigned short)(u >> 16);
}
static __device__ __forceinline__ bf16x8 as_bf(ushort8 v) {
    union { ushort8 u; bf16x8 b; } x; x.u = v; return x.b;
}
// async global->LDS, 16B per lane. LDS dest = wave-uniform base + lane*16.
static __device__ __forceinline__ void gll16(const void* g, void* l) {
    __builtin_amdgcn_global_load_lds(
        (const __attribute__((address_space(1))) void*)g,
        (__attribute__((address_space(3))) void*)l, 16, 0, 0);
}

// ---------------------------------------------------------------------------
// f32 -> bf16 convert (8 elems/thread)
// ---------------------------------------------------------------------------
__global__ void cvt_bf16(const float* __restrict__ in, unsigned short* __restrict__ out,
                         int n8) {
    int i = blockIdx.x * 256 + threadIdx.x;
    if (i >= n8) return;
    const float4* p = (const float4*)(in + (size_t)i * 8);
    float4 a = p[0], b = p[1];
    ushort8 o = { f2bf(a.x), f2bf(a.y), f2bf(a.z), f2bf(a.w),
                  f2bf(b.x), f2bf(b.y), f2bf(b.z), f2bf(b.w) };
    *(ushort8*)(out + (size_t)i * 8) = o;
}

// ---------------------------------------------------------------------------
// transpose + convert: in [K][N] f32 -> out [N][K] bf16. 64x64 tiles.
// ---------------------------------------------------------------------------
__global__ void tconv_bf16(const float* __restrict__ in, unsigned short* __restrict__ out,
                           int K, int N) {
    __shared__ float t[64][65];
    const int tid = threadIdx.x;
    const int n0 = blockIdx.x * 64, k0 = blockIdx.y * 64;
#pragma unroll
    for (int i = 0; i < 4; i++) {
        int idx = tid + 256 * i;
        int r = idx >> 4, c4 = (idx & 15) * 4;
        float4 v = *(const float4*)(in + (size_t)(k0 + r) * N + n0 + c4);
        t[r][c4] = v.x; t[r][c4 + 1] = v.y; t[r][c4 + 2] = v.z; t[r][c4 + 3] = v.w;
    }
    __syncthreads();
#pragma unroll
    for (int i = 0; i < 2; i++) {
        int idx = tid + 256 * i;
        int nl = idx >> 3, k8 = (idx & 7) * 8;
        ushort8 o;
#pragma unroll
        for (int j = 0; j < 8; j++) o[j] = f2bf(t[k8 + j][nl]);
        *(ushort8*)(out + (size_t)(n0 + nl) * K + k0 + k8) = o;
    }
}

// ---------------------------------------------------------------------------
// GEMM (m97-structure): C[M,N] = A[M,K](bf16) * BT[N,K](bf16)^T + bias
// EPI=0: Q (prescaled by 0.125*log2e) and K stored [b][h][l][64];
//        V stored TRANSPOSED [b][h][d][l] (so attn can gll16-stage V^T).
// EPI=1: plain f32 C
// ---------------------------------------------------------------------------
template <int EPI>
__global__ __launch_bounds__(256, 2)
void gemm_bf16(const unsigned short* __restrict__ A,
               const unsigned short* __restrict__ BT,
               const float* __restrict__ bias,
               unsigned short* __restrict__ qh, unsigned short* __restrict__ kh,
               unsigned short* __restrict__ vt,
               float* __restrict__ Cf,
               int K, int mtiles, int Ncols)
{
    __shared__ unsigned short smem[2 * 128 * 64];
    unsigned short* As = smem;
    unsigned short* Bs = smem + 128 * 64;

    const int tid = threadIdx.x;
    const int wid = tid >> 6, lane = tid & 63;
    const int g = lane >> 4, c = lane & 15;
    const int wr = (wid >> 1) * 64, wc = (wid & 1) * 64;

    const int nwg = gridDim.x;
    const int swz = ((int)blockIdx.x & 7) * (nwg >> 3) + ((int)blockIdx.x >> 3);
    const int bm = (swz % mtiles) * 128;
    const int bn = (swz / mtiles) * 128;

    const int srow = lane >> 3;
    const int scol8 = ((lane & 7) ^ srow) * 8;
    const size_t arow0 = (size_t)(bm + wid * 8 + srow);
    const size_t brow0 = (size_t)(bn + wid * 8 + srow);

    f32x4 acc[4][4] = {};

    for (int k0 = 0; k0 < K; k0 += 64) {
        __syncthreads();
#pragma unroll
        for (int t = 0; t < 4; t++) {
            gll16(A + (arow0 + t * 32) * K + k0 + scol8,
                  (char*)As + t * 4096 + wid * 1024);
            gll16(BT + (brow0 + t * 32) * K + k0 + scol8,
                  (char*)Bs + t * 4096 + wid * 1024);
        }
        __syncthreads();
#pragma unroll
        for (int ks = 0; ks < 2; ks++) {
            bf16x8 af[4], bfr[4];
#pragma unroll
            for (int mi = 0; mi < 4; mi++) {
                int row = wr + mi * 16 + c;
                int off = row * 128 + ((ks * 64 + g * 16) ^ ((c & 7) << 4));
                af[mi] = as_bf(*(const ushort8*)((const char*)As + off));
            }
#pragma unroll
            for (int ni = 0; ni < 4; ni++) {
                int row = wc + ni * 16 + c;
                int off = row * 128 + ((ks * 64 + g * 16) ^ ((c & 7) << 4));
                bfr[ni] = as_bf(*(const ushort8*)((const char*)Bs + off));
            }
#pragma unroll
            for (int mi = 0; mi < 4; mi++)
#pragma unroll
                for (int ni = 0; ni < 4; ni++)
                    acc[mi][ni] = __builtin_amdgcn_mfma_f32_16x16x32_bf16(
                        af[mi], bfr[ni], acc[mi][ni], 0, 0, 0);
        }
    }

    if (EPI == 1) {
#pragma unroll
        for (int mi = 0; mi < 4; mi++)
#pragma unroll
            for (int ni = 0; ni < 4; ni++)
#pragma unroll
                for (int r = 0; r < 4; r++) {
                    int m = bm + wr + mi * 16 + g * 4 + r;
                    int n = bn + wc + ni * 16 + c;
                    Cf[(size_t)m * Ncols + n] = acc[mi][ni][r] + bias[n];
                }
    } else {
        const int b = bm >> 10, lb = bm & 1023;
#pragma unroll
        for (int nh = 0; nh < 2; nh++) {
            int n0 = bn + nh * 64;
            int region = n0 >> 10;
            int h = (n0 & 1023) >> 6;
            __syncthreads();
            if (region < 2) {
                // Q/K: [b][h][l][64] via LDS [128 l][64 d]
                float qscale = (region == 0) ? 0.1803368801f : 1.0f;  // 0.125*log2(e)
                if ((wid & 1) == nh) {
#pragma unroll
                    for (int mi = 0; mi < 4; mi++)
#pragma unroll
                        for (int ni = 0; ni < 4; ni++)
#pragma unroll
                            for (int r = 0; r < 4; r++) {
                                int row = wr + mi * 16 + g * 4 + r;
                                int col = ni * 16 + c;
                                float v = (acc[mi][ni][r] + bias[n0 + col]) * qscale;
                                smem[row * 64 + col] = f2bf(v);
                            }
                }
                __syncthreads();
                unsigned short* dst = region == 0 ? qh : kh;
#pragma unroll
                for (int i = 0; i < 4; i++) {
                    int idx = tid + 256 * i;
                    int row = idx >> 3, c8 = (idx & 7) * 8;
                    ushort8 v = *(const ushort8*)&smem[row * 64 + c8];
                    *(ushort8*)(dst + ((size_t)((b * 16 + h) * 1024 + lb + row)) * 64 + c8) = v;
                }
            } else {
                // V: transposed [b][h][d][l] via LDS [64 d][128 l] (XOR-swz rows)
                if ((wid & 1) == nh) {
#pragma unroll
                    for (int mi = 0; mi < 4; mi++)
#pragma unroll
                        for (int ni = 0; ni < 4; ni++)
#pragma unroll
                            for (int r = 0; r < 4; r++) {
                                int l = wr + mi * 16 + g * 4 + r;   // 0..127
                                int d = ni * 16 + c;                // 0..63
                                float v = acc[mi][ni][r] + bias[n0 + d];
                                smem[d * 128 + (l ^ ((d & 7) << 3))] = f2bf(v);
                            }
                }
                __syncthreads();
#pragma unroll
                for (int i = 0; i < 4; i++) {
                    int idx = tid + 256 * i;
                    int d = idx >> 4, l8 = idx & 15;
                    ushort8 v = *(const ushort8*)&smem[d * 128 + ((l8 * 8) ^ ((d & 7) << 3))];
                    *(ushort8*)(vt + ((size_t)((b * 16 + h) * 64 + d)) * 1024 + lb + l8 * 8) = v;
                }
            }
        }
    }
}

// ---------------------------------------------------------------------------
// Attention pass 1 (stats): lr[bh][q] = -log2( sum_k exp2(s) ). No LDS, no
// barriers. 4 independent waves/block, each owns 16 q-rows. Swapped QK^T:
// lane (g,c) holds 4 kcols of q-row c -> lane-local mask+exp2+sum.
// ---------------------------------------------------------------------------
__global__ __launch_bounds__(256)
void attn_stats(const unsigned short* __restrict__ qh,
                const unsigned short* __restrict__ kh,
                float* __restrict__ lrs)
{
    const int tid = threadIdx.x, wid = tid >> 6, lane = tid & 63;
    const int g = lane >> 4, c = lane & 15;
    const int task = blockIdx.x * 4 + wid;     // 8192 tasks
    const int bh = task >> 6;
    const int grp = task & 63;                 // 16-row q-group
    const int q0 = grp * 16;
    const int ntiles = (grp >> 2) + 1;         // 64-key tiles

    const size_t baseKV = (size_t)bh * 65536;
    const int qrow = q0 + c;
    bf16x8 qa0 = as_bf(*(const ushort8*)(qh + baseKV + (size_t)qrow * 64 + g * 8));
    bf16x8 qa1 = as_bf(*(const ushort8*)(qh + baseKV + (size_t)qrow * 64 + 32 + g * 8));

    float lsum = 0.f;
    const unsigned short* kbase = kh + baseKV + (size_t)c * 64 + g * 8;
    for (int kt = 0; kt < ntiles; ++kt) {
#pragma unroll
        for (int a = 0; a < 4; a++) {
            const unsigned short* kr = kbase + (size_t)(kt * 64 + a * 16) * 64;
            bf16x8 k0 = as_bf(*(const ushort8*)(kr));
            bf16x8 k1 = as_bf(*(const ushort8*)(kr + 32));
            f32x4 sa = {0.f, 0.f, 0.f, 0.f};
            sa = __builtin_amdgcn_mfma_f32_16x16x32_bf16(k0, qa0, sa, 0, 0, 0);
            sa = __builtin_amdgcn_mfma_f32_16x16x32_bf16(k1, qa1, sa, 0, 0, 0);
            int kb = kt * 64 + a * 16 + g * 4;
#pragma unroll
            for (int r = 0; r < 4; r++) {
                float sv = (kb + r > qrow) ? -1e9f : sa[r];
                lsum += __builtin_amdgcn_exp2f(sv);
            }
        }
    }
    lsum += __shfl_xor(lsum, 16);
    lsum += __shfl_xor(lsum, 32);
    if (lane < 16) lrs[(size_t)bh * 1024 + q0 + lane] = -__log2f(lsum);
}

// ---------------------------------------------------------------------------
// Attention pass 2: block = (qt of 64 q-rows, bh), 4 waves (16 q-rows each).
// K and V^T staged via gll16 (pre-swizzled source). p = exp2(s + lr) is
// normalized at the exponent -> attn stored straight from registers (f32 NT).
// P packed bf16 (cvt_pk) into per-wave LDS, PV same-wave. LDS 24 KB.
// ---------------------------------------------------------------------------
__global__ __launch_bounds__(256, 2)
void attn_pv(const unsigned short* __restrict__ qh,
             const unsigned short* __restrict__ kh,
             const unsigned short* __restrict__ vt,
             const float* __restrict__ lrs,
             float* __restrict__ attn, unsigned short* __restrict__ ob)
{
    __shared__ char smem[24576];
    char* Ks = smem;                 // [64 k][64 d] bf16, XOR-swz
    char* Vs = smem + 8192;          // [64 d][64 k] bf16, XOR-swz
    char* Ps = smem + 16384;         // per-wave [16 q][64 k] bf16, XOR-swz

    const int qt = blockIdx.x;       // 0..15
    const int bh = blockIdx.y;
    const int q0 = qt * 64;
    const int ntiles = qt + 1;

    const int tid = threadIdx.x, wid = tid >> 6, lane = tid & 63;
    const int g = lane >> 4, c = lane & 15;

    const size_t baseKV = (size_t)bh * 65536;
    const int qrow = q0 + wid * 16 + c;

    bf16x8 qa[2];
    qa[0] = as_bf(*(const ushort8*)(qh + baseKV + (size_t)qrow * 64 + g * 8));
    qa[1] = as_bf(*(const ushort8*)(qh + baseKV + (size_t)qrow * 64 + 32 + g * 8));
    const float lr = lrs[(size_t)bh * 1024 + qrow];

    const int srow = lane >> 3;
    const int scol8 = ((lane & 7) ^ srow) * 8;   // pre-swizzled source col-chunk

    char* Pw = Ps + wid * 2048;
    float* attnR = attn + (size_t)bh * (1024 * 1024) + (size_t)qrow * 1024;

    f32x4 oacc[4] = {};

    for (int kt = 0; kt < ntiles; ++kt) {
        __syncthreads();   // prev tile's Ks/Vs consumers done
        const unsigned short* kb = kh + baseKV + (size_t)kt * 4096;
        const unsigned short* vb = vt + baseKV + kt * 64;
        gll16(kb + (size_t)(wid * 8 + srow) * 64 + scol8, Ks + wid * 1024);
        gll16(kb + (size_t)(32 + wid * 8 + srow) * 64 + scol8, Ks + 4096 + wid * 1024);
        gll16(vb + (size_t)(wid * 8 + srow) * 1024 + scol8, Vs + wid * 1024);
        gll16(vb + (size_t)(32 + wid * 8 + srow) * 1024 + scol8, Vs + 4096 + wid * 1024);
        __syncthreads();   // staged data ready (barrier drains vmcnt)

        // swapped QK^T + fused-normalized exp + direct attn store + P pack
#pragma unroll
        for (int a = 0; a < 4; a++) {
            int krow = a * 16 + c;
            f32x4 sa = {0.f, 0.f, 0.f, 0.f};
#pragma unroll
            for (int ks = 0; ks < 2; ks++) {
                int off = krow * 128 + ((ks * 64 + g * 16) ^ ((c & 7) << 4));
                bf16x8 kf = as_bf(*(const ushort8*)(Ks + off));
                sa = __builtin_amdgcn_mfma_f32_16x16x32_bf16(kf, qa[ks], sa, 0, 0, 0);
            }
            int kb4 = kt * 64 + a * 16 + g * 4;
            f32x4 pv;
            pv[0] = __builtin_amdgcn_exp2f((kb4 + 0 > qrow) ? -1e9f : sa[0] + lr);
            pv[1] = __builtin_amdgcn_exp2f((kb4 + 1 > qrow) ? -1e9f : sa[1] + lr);
            pv[2] = __builtin_amdgcn_exp2f((kb4 + 2 > qrow) ? -1e9f : sa[2] + lr);
            pv[3] = __builtin_amdgcn_exp2f((kb4 + 3 > qrow) ? -1e9f : sa[3] + lr);
            __builtin_nontemporal_store(pv, (f32x4*)(attnR + kb4));
            uint2 pw;
            asm("v_cvt_pk_bf16_f32 %0, %1, %2" : "=v"(pw.x) : "v"(pv[0]), "v"(pv[1]));
            asm("v_cvt_pk_bf16_f32 %0, %1, %2" : "=v"(pw.y) : "v"(pv[2]), "v"(pv[3]));
            *(uint2*)(Pw + c * 128 + ((a * 32 + g * 8) ^ ((c & 7) << 4))) = pw;
        }

        // PV: A = this wave's P rows (same-wave RAW, in-order), B = Vs
#pragma unroll
        for (int ks = 0; ks < 2; ks++) {
            int aoff = c * 128 + ((ks * 64 + g * 16) ^ ((c & 7) << 4));
            bf16x8 pa = as_bf(*(const ushort8*)(Pw + aoff));
#pragma unroll
            for (int ni = 0; ni < 4; ni++) {
                int d = ni * 16 + c;
                int voff = d * 128 + ((ks * 64 + g * 16) ^ ((d & 7) << 4));
                bf16x8 vf = as_bf(*(const ushort8*)(Vs + voff));
                oacc[ni] = __builtin_amdgcn_mfma_f32_16x16x32_bf16(pa, vf, oacc[ni], 0, 0, 0);
            }
        }
    }

    // zero-fill upper k-tiles (d_out is poisoned; every element must be written)
    {
        f32x4 z = {0.f, 0.f, 0.f, 0.f};
        float* zb = attn + (size_t)bh * (1024 * 1024) + (size_t)q0 * 1024;
        for (int kt = ntiles; kt < 16; ++kt) {
#pragma unroll
            for (int i = 0; i < 4; i++) {
                int idx = tid + 256 * i;
                int row = idx >> 4, c4 = (idx & 15) << 2;
                __builtin_nontemporal_store(z, (f32x4*)(zb + (size_t)row * 1024 + kt * 64 + c4));
            }
        }
    }

    // O store (already normalized: P was normalized) via LDS roundtrip -> bf16
    __syncthreads();
#pragma unroll
    for (int ni = 0; ni < 4; ni++)
#pragma unroll
        for (int r = 0; r < 4; r++) {
            int row = wid * 16 + g * 4 + r;   // 0..63
            int d = ni * 16 + c;
            int off = row * 128 + ((d * 2) ^ ((row & 7) << 4));
            *(unsigned short*)(Ks + off) = f2bf(oacc[ni][r]);
        }
    __syncthreads();
    {
        const int b = bh >> 4, h = bh & 15;
#pragma unroll
        for (int i = 0; i < 2; i++) {
            int idx = tid + 256 * i;
            int row = idx >> 3, c8 = idx & 7;
            int off = row * 128 + ((c8 * 16) ^ ((row & 7) << 4));
            ushort8 v = *(const ushort8*)(Ks + off);
            *(ushort8*)(ob + ((size_t)(b * 1024 + q0 + row)) * 1024 + h * 64 + c8 * 8) = v;
        }
    }
}

// ---------------------------------------------------------------------------
// LayerNorm(y + x) -> out
// ---------------------------------------------------------------------------
__global__ __launch_bounds__(256, 2)
void ln_kernel(const float* __restrict__ y, const float* __restrict__ x,
               const float* __restrict__ gamma, const float* __restrict__ beta,
               float* __restrict__ out)
{
    const int m = blockIdx.x;
    const int tid = threadIdx.x;
    const int wid = tid >> 6, lane = tid & 63;
    float4 vy = *(const float4*)(y + (size_t)m * 1024 + tid * 4);
    float4 vx = *(const float4*)(x + (size_t)m * 1024 + tid * 4);
    float4 v = {vy.x + vx.x, vy.y + vx.y, vy.z + vx.z, vy.w + vx.w};
    float s1 = v.x + v.y + v.z + v.w;
    float s2 = v.x * v.x + v.y * v.y + v.z * v.z + v.w * v.w;
#pragma unroll
    for (int d = 1; d < 64; d <<= 1) {
        s1 += __shfl_xor(s1, d);
        s2 += __shfl_xor(s2, d);
    }
    __shared__ float red1[4], red2[4];
    if (lane == 0) { red1[wid] = s1; red2[wid] = s2; }
    __syncthreads();
    float t1 = red1[0] + red1[1] + red1[2] + red1[3];
    float t2 = red2[0] + red2[1] + red2[2] + red2[3];
    float mean = t1 * (1.f / 1024.f);
    float var = t2 * (1.f / 1024.f) - mean * mean;
    float rstd = rsqrtf(var + 1e-5f);
    float4 g4 = *(const float4*)(gamma + tid * 4);
    float4 b4 = *(const float4*)(beta + tid * 4);
    float4 o;
    o.x = g4.x * (v.x - mean) * rstd + b4.x;
    o.y = g4.y * (v.y - mean) * rstd + b4.y;
    o.z = g4.z * (v.z - mean) * rstd + b4.z;
    o.w = g4.w * (v.w - mean) * rstd + b4.w;
    *(float4*)(out + (size_t)m * 1024 + tid * 4) = o;
}

// ---------------------------------------------------------------------------
extern "C" void kernel_launch(void* const* d_in, const int* in_sizes, int n_in,
                              void* d_out, int out_size, void* d_ws, size_t ws_size,
                              hipStream_t stream)
{
    const float* x      = (const float*)d_in[0];
    // d_in[1] = mask — causal, implemented analytically
    const float* W_qkv  = (const float*)d_in[2];
    const float* b_qkv  = (const float*)d_in[3];
    const float* W_proj = (const float*)d_in[4];
    const float* b_proj = (const float*)d_in[5];
    const float* gamma  = (const float*)d_in[6];
    const float* beta   = (const float*)d_in[7];

    float* out  = (float*)d_out;
    float* attn = out + (size_t)8 * 1024 * 1024;

    const size_t E = (size_t)8192 * 1024;
    unsigned short* ws = (unsigned short*)d_ws;
    unsigned short* qh     = ws;                     // bf16 [B][H][L][64]
    unsigned short* kh     = qh + E;                 // bf16 [B][H][L][64]
    unsigned short* vt     = kh + E;                 // bf16 [B][H][64][L]  (transposed)
    unsigned short* xb     = vt + E;                 // bf16 [8192][1024]
    unsigned short* wqkvT  = xb + E;                 // bf16 [3072][1024]
    unsigned short* wprojT = wqkvT + (size_t)3072 * 1024;
    unsigned short* ob     = wprojT + (size_t)1024 * 1024;  // bf16 [8192][1024]
    float* lrs  = (float*)(ob + E);                  // f32 [128][1024]
    float* yb   = (float*)(void*)qh;                 // overlays qh+kh (dead after attn)

    cvt_bf16<<<4096, 256, 0, stream>>>(x, xb, (int)(E / 8));
    tconv_bf16<<<dim3(48, 16), 256, 0, stream>>>(W_qkv, wqkvT, 1024, 3072);
    tconv_bf16<<<dim3(16, 16), 256, 0, stream>>>(W_proj, wprojT, 1024, 1024);

    gemm_bf16<0><<<1536, 256, 0, stream>>>(xb, wqkvT, b_qkv,
                                           qh, kh, vt, nullptr, 1024, 64, 3072);
    attn_stats<<<2048, 256, 0, stream>>>(qh, kh, lrs);
    attn_pv<<<dim3(16, 128), 256, 0, stream>>>(qh, kh, vt, lrs, attn, ob);
    gemm_bf16<1><<<512, 256, 0, stream>>>(ob, wprojT, b_proj,
                                          nullptr, nullptr, nullptr, yb, 1024, 64, 1024);
    ln_kernel<<<8192, 256, 0, stream>>>(yb, x, gamma, beta, out);
}

// Round 8
// 270.774 us; speedup vs baseline: 1.5108x; 1.4938x over previous
//
#include <hip/hip_runtime.h>

typedef __attribute__((ext_vector_type(4))) float f32x4;
typedef __attribute__((ext_vector_type(8))) __bf16 bf16x8;
typedef __attribute__((ext_vector_type(8))) unsigned short ushort8;

static __device__ __forceinline__ unsigned short f2bf(float f) {
    unsigned int u = __float_as_uint(f);
    u += 0x7fffu + ((u >> 16) & 1u);   // round-to-nearest-even
    return (unsigned short)(u >> 16);
}
static __device__ __forceinline__ float bf2f(unsigned short u) {
    return __uint_as_float((unsigned int)u << 16);
}
static __device__ __forceinline__ bf16x8 as_bf(ushort8 v) {
    union { ushort8 u; bf16x8 b; } x; x.u = v; return x.b;
}
// async global->LDS, 16B per lane. LDS dest = wave-uniform base + lane*16.
static __device__ __forceinline__ void gll16(const void* g, void* l) {
    __builtin_amdgcn_global_load_lds(
        (const __attribute__((address_space(1))) void*)g,
        (__attribute__((address_space(3))) void*)l, 16, 0, 0);
}

// ---------------------------------------------------------------------------
// f32 -> bf16 convert (8 elems/thread)
// ---------------------------------------------------------------------------
__global__ void cvt_bf16(const float* __restrict__ in, unsigned short* __restrict__ out,
                         int n8) {
    int i = blockIdx.x * 256 + threadIdx.x;
    if (i >= n8) return;
    const float4* p = (const float4*)(in + (size_t)i * 8);
    float4 a = p[0], b = p[1];
    ushort8 o = { f2bf(a.x), f2bf(a.y), f2bf(a.z), f2bf(a.w),
                  f2bf(b.x), f2bf(b.y), f2bf(b.z), f2bf(b.w) };
    *(ushort8*)(out + (size_t)i * 8) = o;
}

// ---------------------------------------------------------------------------
// transpose + convert: in [K][N] f32 -> out [N][K] bf16. 64x64 tiles.
// ---------------------------------------------------------------------------
__global__ void tconv_bf16(const float* __restrict__ in, unsigned short* __restrict__ out,
                           int K, int N) {
    __shared__ float t[64][65];
    const int tid = threadIdx.x;
    const int n0 = blockIdx.x * 64, k0 = blockIdx.y * 64;
#pragma unroll
    for (int i = 0; i < 4; i++) {
        int idx = tid + 256 * i;
        int r = idx >> 4, c4 = (idx & 15) * 4;
        float4 v = *(const float4*)(in + (size_t)(k0 + r) * N + n0 + c4);
        t[r][c4] = v.x; t[r][c4 + 1] = v.y; t[r][c4 + 2] = v.z; t[r][c4 + 3] = v.w;
    }
    __syncthreads();
#pragma unroll
    for (int i = 0; i < 2; i++) {
        int idx = tid + 256 * i;
        int nl = idx >> 3, k8 = (idx & 7) * 8;
        ushort8 o;
#pragma unroll
        for (int j = 0; j < 8; j++) o[j] = f2bf(t[k8 + j][nl]);
        *(ushort8*)(out + (size_t)(n0 + nl) * K + k0 + k8) = o;
    }
}

// ---------------------------------------------------------------------------
// GEMM (m97-structure): C[M,N] = A[M,K](bf16) * BT[N,K](bf16)^T + bias
// EPI=0: Q (prescaled by 0.125*log2e) and K stored [b][h][l][64];
//        V stored TRANSPOSED [b][h][d][l] (so attn can gll16-stage V^T).
// EPI=1: plain f32 C
// ---------------------------------------------------------------------------
template <int EPI>
__global__ __launch_bounds__(256, 2)
void gemm_bf16(const unsigned short* __restrict__ A,
               const unsigned short* __restrict__ BT,
               const float* __restrict__ bias,
               unsigned short* __restrict__ qh, unsigned short* __restrict__ kh,
               unsigned short* __restrict__ vt,
               float* __restrict__ Cf,
               int K, int mtiles, int Ncols)
{
    __shared__ unsigned short smem[2 * 128 * 64];
    unsigned short* As = smem;
    unsigned short* Bs = smem + 128 * 64;

    const int tid = threadIdx.x;
    const int wid = tid >> 6, lane = tid & 63;
    const int g = lane >> 4, c = lane & 15;
    const int wr = (wid >> 1) * 64, wc = (wid & 1) * 64;

    const int nwg = gridDim.x;
    const int swz = ((int)blockIdx.x & 7) * (nwg >> 3) + ((int)blockIdx.x >> 3);
    const int bm = (swz % mtiles) * 128;
    const int bn = (swz / mtiles) * 128;

    const int srow = lane >> 3;
    const int scol8 = ((lane & 7) ^ srow) * 8;
    const size_t arow0 = (size_t)(bm + wid * 8 + srow);
    const size_t brow0 = (size_t)(bn + wid * 8 + srow);

    f32x4 acc[4][4] = {};

    for (int k0 = 0; k0 < K; k0 += 64) {
        __syncthreads();
#pragma unroll
        for (int t = 0; t < 4; t++) {
            gll16(A + (arow0 + t * 32) * K + k0 + scol8,
                  (char*)As + t * 4096 + wid * 1024);
            gll16(BT + (brow0 + t * 32) * K + k0 + scol8,
                  (char*)Bs + t * 4096 + wid * 1024);
        }
        __syncthreads();
#pragma unroll
        for (int ks = 0; ks < 2; ks++) {
            bf16x8 af[4], bfr[4];
#pragma unroll
            for (int mi = 0; mi < 4; mi++) {
                int row = wr + mi * 16 + c;
                int off = row * 128 + ((ks * 64 + g * 16) ^ ((c & 7) << 4));
                af[mi] = as_bf(*(const ushort8*)((const char*)As + off));
            }
#pragma unroll
            for (int ni = 0; ni < 4; ni++) {
                int row = wc + ni * 16 + c;
                int off = row * 128 + ((ks * 64 + g * 16) ^ ((c & 7) << 4));
                bfr[ni] = as_bf(*(const ushort8*)((const char*)Bs + off));
            }
#pragma unroll
            for (int mi = 0; mi < 4; mi++)
#pragma unroll
                for (int ni = 0; ni < 4; ni++)
                    acc[mi][ni] = __builtin_amdgcn_mfma_f32_16x16x32_bf16(
                        af[mi], bfr[ni], acc[mi][ni], 0, 0, 0);
        }
    }

    if (EPI == 1) {
#pragma unroll
        for (int mi = 0; mi < 4; mi++)
#pragma unroll
            for (int ni = 0; ni < 4; ni++)
#pragma unroll
                for (int r = 0; r < 4; r++) {
                    int m = bm + wr + mi * 16 + g * 4 + r;
                    int n = bn + wc + ni * 16 + c;
                    Cf[(size_t)m * Ncols + n] = acc[mi][ni][r] + bias[n];
                }
    } else {
        const int b = bm >> 10, lb = bm & 1023;
#pragma unroll
        for (int nh = 0; nh < 2; nh++) {
            int n0 = bn + nh * 64;
            int region = n0 >> 10;
            int h = (n0 & 1023) >> 6;
            __syncthreads();
            if (region < 2) {
                // Q/K: [b][h][l][64] via LDS [128 l][64 d]
                float qscale = (region == 0) ? 0.1803368801f : 1.0f;  // 0.125*log2(e)
                if ((wid & 1) == nh) {
#pragma unroll
                    for (int mi = 0; mi < 4; mi++)
#pragma unroll
                        for (int ni = 0; ni < 4; ni++)
#pragma unroll
                            for (int r = 0; r < 4; r++) {
                                int row = wr + mi * 16 + g * 4 + r;
                                int col = ni * 16 + c;
                                float v = (acc[mi][ni][r] + bias[n0 + col]) * qscale;
                                smem[row * 64 + col] = f2bf(v);
                            }
                }
                __syncthreads();
                unsigned short* dst = region == 0 ? qh : kh;
#pragma unroll
                for (int i = 0; i < 4; i++) {
                    int idx = tid + 256 * i;
                    int row = idx >> 3, c8 = (idx & 7) * 8;
                    ushort8 v = *(const ushort8*)&smem[row * 64 + c8];
                    *(ushort8*)(dst + ((size_t)((b * 16 + h) * 1024 + lb + row)) * 64 + c8) = v;
                }
            } else {
                // V: transposed [b][h][d][l] via LDS [64 d][128 l] (XOR-swz rows)
                if ((wid & 1) == nh) {
#pragma unroll
                    for (int mi = 0; mi < 4; mi++)
#pragma unroll
                        for (int ni = 0; ni < 4; ni++)
#pragma unroll
                            for (int r = 0; r < 4; r++) {
                                int l = wr + mi * 16 + g * 4 + r;   // 0..127
                                int d = ni * 16 + c;                // 0..63
                                float v = acc[mi][ni][r] + bias[n0 + d];
                                smem[d * 128 + (l ^ ((d & 7) << 3))] = f2bf(v);
                            }
                }
                __syncthreads();
#pragma unroll
                for (int i = 0; i < 4; i++) {
                    int idx = tid + 256 * i;
                    int d = idx >> 4, l8 = idx & 15;
                    ushort8 v = *(const ushort8*)&smem[d * 128 + ((l8 * 8) ^ ((d & 7) << 3))];
                    *(ushort8*)(vt + ((size_t)((b * 16 + h) * 64 + d)) * 1024 + lb + l8 * 8) = v;
                }
            }
        }
    }
}

// ---------------------------------------------------------------------------
// Attention (round-2 skeleton, lean passes). Block = (bh, qt of 64 q-rows),
// 4 waves, wave owns 16 q-rows. Swapped QK^T (mfma(K,Q)) -> lane-local
// scores; no-max exp2 softmax.
// Pass 1: K-only staging, lsum accumulate (no shuffles in loop).
// Pass 2: K+V^T gll16 staging, p=exp2(s+lr) (normalized at exponent),
//         P->Ps via cvt_pk 8B write, PV same-wave, attn store 256B-coalesced
//         from Ps (no rinv), O store via LDS roundtrip (no rinv).
// LDS: Ks 8K | Vs 8K | Ps 8K = 24 KB.
// ---------------------------------------------------------------------------
__global__ __launch_bounds__(256, 2)
void attn_kernel(const unsigned short* __restrict__ qh,
                 const unsigned short* __restrict__ kh,
                 const unsigned short* __restrict__ vt,
                 float* __restrict__ attn, unsigned short* __restrict__ ob)
{
    __shared__ char smem[24576];
    char* Ks = smem;                 // [64 k][64 d] bf16, XOR-swz
    char* Vs = smem + 8192;          // [64 d][64 k] bf16, XOR-swz
    char* Ps = smem + 16384;         // per-wave [16 q][64 k] bf16, XOR-swz

    const int bh = blockIdx.x;       // b*16 + h
    const int qt = blockIdx.y;       // 0..15
    const int q0 = qt * 64;
    const int ntiles = qt + 1;

    const int tid = threadIdx.x, wid = tid >> 6, lane = tid & 63;
    const int g = lane >> 4, c = lane & 15;

    const size_t baseKV = (size_t)bh * 65536;
    const int qrow = q0 + wid * 16 + c;

    bf16x8 qa[2];
    qa[0] = as_bf(*(const ushort8*)(qh + baseKV + (size_t)qrow * 64 + g * 8));
    qa[1] = as_bf(*(const ushort8*)(qh + baseKV + (size_t)qrow * 64 + 32 + g * 8));

    const int srow = lane >> 3;
    const int scol8 = ((lane & 7) ^ srow) * 8;   // pre-swizzled source col-chunk

    // ---- pass 1: lsum only (swapped QK^T, lane-local) ----
    float lsum = 0.f;
    for (int kt = 0; kt < ntiles; ++kt) {
        const unsigned short* kb = kh + baseKV + (size_t)kt * 4096;
        __syncthreads();
        gll16(kb + (size_t)(wid * 8 + srow) * 64 + scol8, Ks + wid * 1024);
        gll16(kb + (size_t)(32 + wid * 8 + srow) * 64 + scol8, Ks + 4096 + wid * 1024);
        __syncthreads();
#pragma unroll
        for (int a = 0; a < 4; a++) {
            int krow = a * 16 + c;
            f32x4 sa = {0.f, 0.f, 0.f, 0.f};
#pragma unroll
            for (int ks = 0; ks < 2; ks++) {
                int off = krow * 128 + ((ks * 64 + g * 16) ^ ((c & 7) << 4));
                bf16x8 kf = as_bf(*(const ushort8*)(Ks + off));
                sa = __builtin_amdgcn_mfma_f32_16x16x32_bf16(kf, qa[ks], sa, 0, 0, 0);
            }
            int kb4 = kt * 64 + a * 16 + g * 4;
#pragma unroll
            for (int r = 0; r < 4; r++)
                lsum += (kb4 + r > qrow) ? 0.f : __builtin_amdgcn_exp2f(sa[r]);
        }
    }
    lsum += __shfl_xor(lsum, 16);
    lsum += __shfl_xor(lsum, 32);
    const float lr = -__log2f(lsum);

    // ---- pass 2: P (normalized), attn store, O accumulate ----
    char* Pw = Ps + wid * 2048;
    float* attnB = attn + (size_t)bh * (1024 * 1024) + (size_t)q0 * 1024;
    f32x4 oacc[4] = {};

    for (int kt = 0; kt < ntiles; ++kt) {
        const unsigned short* kb = kh + baseKV + (size_t)kt * 4096;
        const unsigned short* vb = vt + baseKV + kt * 64;
        __syncthreads();   // prev tile's Ks/Vs/Ps consumers done
        gll16(kb + (size_t)(wid * 8 + srow) * 64 + scol8, Ks + wid * 1024);
        gll16(kb + (size_t)(32 + wid * 8 + srow) * 64 + scol8, Ks + 4096 + wid * 1024);
        gll16(vb + (size_t)(wid * 8 + srow) * 1024 + scol8, Vs + wid * 1024);
        gll16(vb + (size_t)(32 + wid * 8 + srow) * 1024 + scol8, Vs + 4096 + wid * 1024);
        __syncthreads();   // staged (barrier drains vmcnt)

#pragma unroll
        for (int a = 0; a < 4; a++) {
            int krow = a * 16 + c;
            f32x4 sa = {0.f, 0.f, 0.f, 0.f};
#pragma unroll
            for (int ks = 0; ks < 2; ks++) {
                int off = krow * 128 + ((ks * 64 + g * 16) ^ ((c & 7) << 4));
                bf16x8 kf = as_bf(*(const ushort8*)(Ks + off));
                sa = __builtin_amdgcn_mfma_f32_16x16x32_bf16(kf, qa[ks], sa, 0, 0, 0);
            }
            int kb4 = kt * 64 + a * 16 + g * 4;
            float p0 = __builtin_amdgcn_exp2f((kb4 + 0 > qrow) ? -1e9f : sa[0] + lr);
            float p1 = __builtin_amdgcn_exp2f((kb4 + 1 > qrow) ? -1e9f : sa[1] + lr);
            float p2 = __builtin_amdgcn_exp2f((kb4 + 2 > qrow) ? -1e9f : sa[2] + lr);
            float p3 = __builtin_amdgcn_exp2f((kb4 + 3 > qrow) ? -1e9f : sa[3] + lr);
            uint2 pw;
            asm("v_cvt_pk_bf16_f32 %0, %1, %2" : "=v"(pw.x) : "v"(p0), "v"(p1));
            asm("v_cvt_pk_bf16_f32 %0, %1, %2" : "=v"(pw.y) : "v"(p2), "v"(p3));
            *(uint2*)(Pw + c * 128 + ((a * 32 + g * 8) ^ ((c & 7) << 4))) = pw;
        }

        // PV: A = own wave's P rows (same-wave RAW, in-order), B = Vs
#pragma unroll
        for (int ks = 0; ks < 2; ks++) {
            int aoff = c * 128 + ((ks * 64 + g * 16) ^ ((c & 7) << 4));
            bf16x8 pa = as_bf(*(const ushort8*)(Pw + aoff));
#pragma unroll
            for (int ni = 0; ni < 4; ni++) {
                int d = ni * 16 + c;
                int voff = d * 128 + ((ks * 64 + g * 16) ^ ((d & 7) << 4));
                bf16x8 vf = as_bf(*(const ushort8*)(Vs + voff));
                oacc[ni] = __builtin_amdgcn_mfma_f32_16x16x32_bf16(pa, vf, oacc[ni], 0, 0, 0);
            }
        }
        __syncthreads();   // all waves' Ps complete before cooperative store

        // attn store: 64 rows x 64 cols, 256B contiguous per row (no rinv)
#pragma unroll
        for (int i = 0; i < 2; i++) {
            int idx = tid + 256 * i;
            int row = idx >> 3, c16 = idx & 7;
            int off = (row >> 4) * 2048 + (row & 15) * 128 + ((c16 * 16) ^ ((row & 7) << 4));
            ushort8 v = *(const ushort8*)(Ps + off);
            float4 f0 = { bf2f(v[0]), bf2f(v[1]), bf2f(v[2]), bf2f(v[3]) };
            float4 f1 = { bf2f(v[4]), bf2f(v[5]), bf2f(v[6]), bf2f(v[7]) };
            float* dp = attnB + (size_t)row * 1024 + kt * 64 + c16 * 8;
            *(float4*)dp = f0;
            *(float4*)(dp + 4) = f1;
        }
    }

    // zero the strictly-upper k-tiles (d_out is poisoned)
    {
        float4 z = {0.f, 0.f, 0.f, 0.f};
        for (int kt = ntiles; kt < 16; ++kt) {
#pragma unroll
            for (int i = 0; i < 4; i++) {
                int idx = tid + 256 * i;
                int row = idx >> 4, c4 = (idx & 15) << 2;
                *(float4*)(attnB + (size_t)row * 1024 + kt * 64 + c4) = z;
            }
        }
    }

    // O store (P normalized -> oacc final) via LDS roundtrip -> bf16
    __syncthreads();
#pragma unroll
    for (int ni = 0; ni < 4; ni++)
#pragma unroll
        for (int r = 0; r < 4; r++) {
            int row = wid * 16 + g * 4 + r;   // 0..63
            int d = ni * 16 + c;
            int off = row * 128 + ((d * 2) ^ ((row & 7) << 4));
            *(unsigned short*)(Ks + off) = f2bf(oacc[ni][r]);
        }
    __syncthreads();
    {
        const int b = bh >> 4, h = bh & 15;
#pragma unroll
        for (int i = 0; i < 2; i++) {
            int idx = tid + 256 * i;
            int row = idx >> 3, c8 = idx & 7;
            int off = row * 128 + ((c8 * 16) ^ ((row & 7) << 4));
            ushort8 v = *(const ushort8*)(Ks + off);
            *(ushort8*)(ob + ((size_t)(b * 1024 + q0 + row)) * 1024 + h * 64 + c8 * 8) = v;
        }
    }
}

// ---------------------------------------------------------------------------
// LayerNorm(y + x) -> out
// ---------------------------------------------------------------------------
__global__ __launch_bounds__(256, 2)
void ln_kernel(const float* __restrict__ y, const float* __restrict__ x,
               const float* __restrict__ gamma, const float* __restrict__ beta,
               float* __restrict__ out)
{
    const int m = blockIdx.x;
    const int tid = threadIdx.x;
    const int wid = tid >> 6, lane = tid & 63;
    float4 vy = *(const float4*)(y + (size_t)m * 1024 + tid * 4);
    float4 vx = *(const float4*)(x + (size_t)m * 1024 + tid * 4);
    float4 v = {vy.x + vx.x, vy.y + vx.y, vy.z + vx.z, vy.w + vx.w};
    float s1 = v.x + v.y + v.z + v.w;
    float s2 = v.x * v.x + v.y * v.y + v.z * v.z + v.w * v.w;
#pragma unroll
    for (int d = 1; d < 64; d <<= 1) {
        s1 += __shfl_xor(s1, d);
        s2 += __shfl_xor(s2, d);
    }
    __shared__ float red1[4], red2[4];
    if (lane == 0) { red1[wid] = s1; red2[wid] = s2; }
    __syncthreads();
    float t1 = red1[0] + red1[1] + red1[2] + red1[3];
    float t2 = red2[0] + red2[1] + red2[2] + red2[3];
    float mean = t1 * (1.f / 1024.f);
    float var = t2 * (1.f / 1024.f) - mean * mean;
    float rstd = rsqrtf(var + 1e-5f);
    float4 g4 = *(const float4*)(gamma + tid * 4);
    float4 b4 = *(const float4*)(beta + tid * 4);
    float4 o;
    o.x = g4.x * (v.x - mean) * rstd + b4.x;
    o.y = g4.y * (v.y - mean) * rstd + b4.y;
    o.z = g4.z * (v.z - mean) * rstd + b4.z;
    o.w = g4.w * (v.w - mean) * rstd + b4.w;
    *(float4*)(out + (size_t)m * 1024 + tid * 4) = o;
}

// ---------------------------------------------------------------------------
extern "C" void kernel_launch(void* const* d_in, const int* in_sizes, int n_in,
                              void* d_out, int out_size, void* d_ws, size_t ws_size,
                              hipStream_t stream)
{
    const float* x      = (const float*)d_in[0];
    // d_in[1] = mask — causal, implemented analytically
    const float* W_qkv  = (const float*)d_in[2];
    const float* b_qkv  = (const float*)d_in[3];
    const float* W_proj = (const float*)d_in[4];
    const float* b_proj = (const float*)d_in[5];
    const float* gamma  = (const float*)d_in[6];
    const float* beta   = (const float*)d_in[7];

    float* out  = (float*)d_out;
    float* attn = out + (size_t)8 * 1024 * 1024;

    const size_t E = (size_t)8192 * 1024;
    unsigned short* ws = (unsigned short*)d_ws;
    unsigned short* qh     = ws;                     // bf16 [B][H][L][64]
    unsigned short* kh     = qh + E;                 // bf16 [B][H][L][64]
    unsigned short* vt     = kh + E;                 // bf16 [B][H][64][L]  (transposed)
    unsigned short* xb     = vt + E;                 // bf16 [8192][1024]
    unsigned short* wqkvT  = xb + E;                 // bf16 [3072][1024]
    unsigned short* wprojT = wqkvT + (size_t)3072 * 1024;
    unsigned short* ob     = wprojT + (size_t)1024 * 1024;  // bf16 [8192][1024]
    float* yb   = (float*)(void*)qh;                 // overlays qh+kh (dead after attn)

    cvt_bf16<<<4096, 256, 0, stream>>>(x, xb, (int)(E / 8));
    tconv_bf16<<<dim3(48, 16), 256, 0, stream>>>(W_qkv, wqkvT, 1024, 3072);
    tconv_bf16<<<dim3(16, 16), 256, 0, stream>>>(W_proj, wprojT, 1024, 1024);

    gemm_bf16<0><<<1536, 256, 0, stream>>>(xb, wqkvT, b_qkv,
                                           qh, kh, vt, nullptr, 1024, 64, 3072);
    attn_kernel<<<dim3(128, 16), 256, 0, stream>>>(qh, kh, vt, attn, ob);
    gemm_bf16<1><<<512, 256, 0, stream>>>(ob, wprojT, b_proj,
                                          nullptr, nullptr, nullptr, yb, 1024, 64, 1024);
    ln_kernel<<<8192, 256, 0, stream>>>(yb, x, gamma, beta, out);
}